// Round 17
// baseline (28216.269 us; speedup 1.0000x reference)
//
#include <hip/hip_runtime.h>
#include <math.h>

// ============================================================================
// LARNN forward, MI355X — persistent kernel, fence-free sc1.
// ALL-F32 (bf16 diverges — chaotic recurrence). Deterministic BN stats.
// Round 17 = round-16 base (15.82 ms, 2 blocks/CU), minus one phase:
//   P6 (gates) folded into P5's epilogue. P5 blocks own 64 rows x 16 base
//   cols x ALL 4 gate slices (gate-interleaved B in LDS -> f4 reads), so
//   after the GEMM each thread has the full pre-activation row-slice:
//   gates + c/hv update + BN-post partials computed in-epilogue.
//   5 phases/step (640 barriers total, was 768). stP -> 4-partial layout.
// ============================================================================

#define T_  128
#define B_  256
#define F_  128
#define H_  512
#define W_  16
#define H4_ 2048
#define EPS_ 1e-5f
#define BH_ (B_*H_)
#define NBLK 512
#define NTHR 512
#define FSTRIDE 32   // uints per flag (128B line)

typedef __attribute__((ext_vector_type(4))) float f4;
typedef __attribute__((ext_vector_type(2))) float f2;
typedef unsigned long long u64;

__device__ __forceinline__ float eluf(float x){ return x > 0.f ? x : expf(x) - 1.f; }
__device__ __forceinline__ float sigf(float x){ return 1.f / (1.f + expf(-x)); }

// ---- LLC-coherent (sc1) relaxed accessors: no cache maintenance emitted ----
__device__ __forceinline__ f4 ld_c(const float* p) {
  union { f4 v; u64 q[2]; } u;
  u.q[0] = __hip_atomic_load((const u64*)p,     __ATOMIC_RELAXED, __HIP_MEMORY_SCOPE_AGENT);
  u.q[1] = __hip_atomic_load((const u64*)p + 1, __ATOMIC_RELAXED, __HIP_MEMORY_SCOPE_AGENT);
  return u.v;
}
__device__ __forceinline__ void st_c(float* p, f4 v) {
  union { f4 v; u64 q[2]; } u; u.v = v;
  __hip_atomic_store((u64*)p,     u.q[0], __ATOMIC_RELAXED, __HIP_MEMORY_SCOPE_AGENT);
  __hip_atomic_store((u64*)p + 1, u.q[1], __ATOMIC_RELAXED, __HIP_MEMORY_SCOPE_AGENT);
}
__device__ __forceinline__ f2 ld2_c(const float* p) {
  union { u64 q; f2 v; } u;
  u.q = __hip_atomic_load((const u64*)p, __ATOMIC_RELAXED, __HIP_MEMORY_SCOPE_AGENT);
  return u.v;
}
__device__ __forceinline__ void st2_c(float* p, f2 v) {
  union { f2 v; u64 q; } u; u.v = v;
  __hip_atomic_store((u64*)p, u.q, __ATOMIC_RELAXED, __HIP_MEMORY_SCOPE_AGENT);
}
__device__ __forceinline__ float ldf_c(const float* p) {
  unsigned u = __hip_atomic_load((const unsigned*)p, __ATOMIC_RELAXED, __HIP_MEMORY_SCOPE_AGENT);
  return __uint_as_float(u);
}
__device__ __forceinline__ void stf_c(float* p, float v) {
  __hip_atomic_store((unsigned*)p, __float_as_uint(v), __ATOMIC_RELAXED, __HIP_MEMORY_SCOPE_AGENT);
}

struct Params {
  const float *x, *W_ih, *b_ih, *W_hh, *Wq_in, *bq_in, *Wq, *bq, *Wk, *bk,
              *Wv, *bv, *Wo, *bo, *W_ac, *b_ac, *g_att, *be_att, *g_post, *be_post;
  float *out, *c, *q, *Qh, *ctx, *attp, *hv, *pre, *Kbuf, *Vbuf, *stA, *stP;
  unsigned *gen, *arr;
};

// Barrier: flag store + block-0 parallel aggregation + gen release.
__device__ __forceinline__ void gbar(unsigned* arr, unsigned* gen, unsigned g) {
  asm volatile("s_waitcnt vmcnt(0) lgkmcnt(0)" ::: "memory");
  __syncthreads();
  const int tid = threadIdx.x;
  if (tid == 0)
    __hip_atomic_store(&arr[blockIdx.x * FSTRIDE], g, __ATOMIC_RELAXED, __HIP_MEMORY_SCOPE_AGENT);
  if (blockIdx.x == 0) {
    if (tid < NBLK) {
      while (__hip_atomic_load(&arr[tid * FSTRIDE], __ATOMIC_RELAXED, __HIP_MEMORY_SCOPE_AGENT) < g)
        __builtin_amdgcn_s_sleep(1);
    }
    __syncthreads();
    if (tid == 0)
      __hip_atomic_store(gen, g, __ATOMIC_RELAXED, __HIP_MEMORY_SCOPE_AGENT);
  } else {
    if (tid == 0) {
      while (__hip_atomic_load(gen, __ATOMIC_RELAXED, __HIP_MEMORY_SCOPE_AGENT) < g)
        __builtin_amdgcn_s_sleep(1);
    }
  }
  __syncthreads();
}

// BN scale/shift from 4-way partial stats st[4][2][512] (stA or stP).
__device__ __forceinline__ void prep4(const float* st, const float* gn, const float* be,
                                      float* scl, float* shf, int tid) {
  if (tid < H_) {
    float S  = ldf_c(st + tid) + ldf_c(st + 1024 + tid) + ldf_c(st + 2048 + tid) + ldf_c(st + 3072 + tid);
    float S2 = ldf_c(st + 512 + tid) + ldf_c(st + 1536 + tid) + ldf_c(st + 2560 + tid) + ldf_c(st + 3584 + tid);
    float mu  = S * (1.f / B_);
    float var = S2 * (1.f / B_) - mu * mu;
    float sc  = rsqrtf(var + EPS_) * gn[tid];
    scl[tid] = sc; shf[tid] = be[tid] - mu * sc;
  }
}

// ---------------------------------------------------------------------------
// Generic 64x32 tile, K-concat of up to 2 segments, 512 threads, 2x2 microtile.
// (Identical to r16; Bs widened to [32][68] rows — indices unchanged.)
// ---------------------------------------------------------------------------
struct GJ {
  const float* A1; int lda1; int K1; int nrm1; int cg1;
  const float* A2; int lda2; int K2; int nrm2; int cg2;
  const float* W1; const float* W2;    // [K][N] row-major, stride N (plain)
  const float* b1; const float* b2; const float* addm;
  float* out; float* stats;
  int N; int m0; int n0; int doElu;
};

__device__ void gemm_tile(const GJ& J, int tid,
                          float (*As)[64][36], float (*Bs)[32][68],
                          const float* scl, const float* shf) {
  const int arow = tid >> 3, akq = (tid & 7) * 4;
  const int bkk = tid >> 4, bnn = (tid & 15) * 2;
  const int ty = tid >> 4, tx = tid & 15;

  float acc[2][2] = {{0.f,0.f},{0.f,0.f}};

  f2 am0 = {0.f,0.f}, am1 = {0.f,0.f};
  if (J.addm) {
    am0 = ld2_c(J.addm + (size_t)(J.m0 + ty * 2)     * J.N + J.n0 + tx * 2);
    am1 = ld2_c(J.addm + (size_t)(J.m0 + ty * 2 + 1) * J.N + J.n0 + tx * 2);
  }

  int buf = 0;
  for (int s = 0; s < 2; ++s) {
    const float* A = s ? J.A2 : J.A1;
    if (!A) break;
    const float* Wp  = s ? J.W2 : J.W1;
    const int K      = s ? J.K2 : J.K1;
    const int lda    = s ? J.lda2 : J.lda1;
    const int nrm    = s ? J.nrm2 : J.nrm1;
    const int cg     = s ? J.cg2 : J.cg1;
    const int nsl    = K >> 5;

    const float* aBase = A + (size_t)(J.m0 + arow) * lda + akq;
    const float* wBase = Wp + (size_t)bkk * J.N + J.n0 + bnn;
    const size_t wSlab = (size_t)32 * J.N;

    f4 aN1 = cg ? ld_c(aBase) : *(const f4*)aBase;
    f4 aN2 = (nsl > 1) ? (cg ? ld_c(aBase + 32) : *(const f4*)(aBase + 32)) : aN1;
    f2 bN1 = *(const f2*)wBase;

    for (int sl = 0; sl < nsl; ++sl) {
      f4 aCur = aN1; aN1 = aN2;
      f2 bCur = bN1;
      if (sl + 2 < nsl) {
        const float* ap = aBase + (size_t)(sl + 2) * 32;
        aN2 = cg ? ld_c(ap) : *(const f4*)ap;
      }
      if (sl + 1 < nsl) bN1 = *(const f2*)(wBase + (size_t)(sl + 1) * wSlab);
      if (nrm) {
        #pragma unroll
        for (int i = 0; i < 4; ++i) {
          int gk = sl * 32 + akq + i;
          aCur[i] = aCur[i] * scl[gk] + shf[gk];
        }
      }
      *(f4*)&As[buf][arow][akq] = aCur;
      *(f2*)&Bs[buf][bkk][bnn] = bCur;
      __syncthreads();
      #pragma unroll
      for (int k = 0; k < 32; k += 2) {
        f2 a0 = *(const f2*)&As[buf][ty * 2][k];
        f2 a1 = *(const f2*)&As[buf][ty * 2 + 1][k];
        f2 b0 = *(const f2*)&Bs[buf][k][tx * 2];
        f2 b1 = *(const f2*)&Bs[buf][k + 1][tx * 2];
        acc[0][0] = fmaf(a0[0], b0[0], acc[0][0]);
        acc[0][1] = fmaf(a0[0], b0[1], acc[0][1]);
        acc[0][0] = fmaf(a0[1], b1[0], acc[0][0]);
        acc[0][1] = fmaf(a0[1], b1[1], acc[0][1]);
        acc[1][0] = fmaf(a1[0], b0[0], acc[1][0]);
        acc[1][1] = fmaf(a1[0], b0[1], acc[1][1]);
        acc[1][0] = fmaf(a1[1], b1[0], acc[1][0]);
        acc[1][1] = fmaf(a1[1], b1[1], acc[1][1]);
      }
      buf ^= 1;
    }
  }

  const int r0 = J.m0 + ty * 2, c0 = J.n0 + tx * 2;
  f2 bias = {0.f, 0.f};
  if (J.b1) bias += *(const f2*)(J.b1 + c0);
  if (J.b2) bias += *(const f2*)(J.b2 + c0);
  f2 v0, v1;
  v0[0] = acc[0][0] + bias[0]; v0[1] = acc[0][1] + bias[1];
  v1[0] = acc[1][0] + bias[0]; v1[1] = acc[1][1] + bias[1];
  if (J.addm) { v0 += am0; v1 += am1; }
  if (J.doElu) {
    v0[0] = eluf(v0[0]); v0[1] = eluf(v0[1]);
    v1[0] = eluf(v1[0]); v1[1] = eluf(v1[1]);
  }
  st2_c(J.out + (size_t)r0 * J.N + c0, v0);
  st2_c(J.out + (size_t)(r0 + 1) * J.N + c0, v1);

  if (J.stats) {   // deterministic per-64-row-tile column partials (32 cols)
    float* Af = (float*)As;
    float* Bf = (float*)Bs;
    __syncthreads();
    Af[ty * 32 + tx * 2]     = v0[0] + v1[0];
    Af[ty * 32 + tx * 2 + 1] = v0[1] + v1[1];
    Bf[ty * 32 + tx * 2]     = v0[0] * v0[0] + v1[0] * v1[0];
    Bf[ty * 32 + tx * 2 + 1] = v0[1] * v0[1] + v1[1] * v1[1];
    __syncthreads();
    if (tid < 32) {
      float S = 0.f, S2 = 0.f;
      #pragma unroll
      for (int y = 0; y < 32; ++y) { S += Af[y * 32 + tid]; S2 += Bf[y * 32 + tid]; }
      const int tm = J.m0 >> 6;
      stf_c(J.stats + tm * 1024 + J.n0 + tid, S);
      stf_c(J.stats + tm * 1024 + 512 + J.n0 + tid, S2);
    }
  }
}

// ---------------------------------------------------------------------------
// P5 specialized: pre-gates GEMM + fused gates/c/hv/BN-partials.
// 128 blocks: m0 = (bid>>5)*64 (4 row-tiles), n0 = (bid&31)*16 (32 col-groups).
// Tile = 64 rows x 16 base-cols x 4 gates. B gate-interleaved in LDS:
// Bs[k][c8*4+g] = W_ac[k][n0+c8+g*512] -> inner-loop B read is one f4.
// val = acc + preHF  (bit-identical to old P5-store -> P6-load path).
// ---------------------------------------------------------------------------
__device__ void gemm_gates(const Params& P, int tid, int bid,
                           float (*As)[64][36], float (*Bs)[32][68],
                           const float* scl, const float* shf) {
  const int m0 = (bid >> 5) * 64, n0 = (bid & 31) * 16;
  const int arow = tid >> 3, akq = (tid & 7) * 4;
  const int kk = tid >> 4, c8 = tid & 15;
  const int ty = tid >> 4, tx = tid & 15;
  const int r0 = m0 + ty * 2;

  // upfront prefetch: preHF (8 scalars) + cold c (2 scalars)
  float am[2][4];
  #pragma unroll
  for (int i = 0; i < 2; ++i)
    #pragma unroll
    for (int gg = 0; gg < 4; ++gg)
      am[i][gg] = ldf_c(P.pre + (size_t)(r0 + i) * H4_ + n0 + tx + gg * 512);
  float cold0 = ldf_c(P.c + (size_t)r0 * H_ + n0 + tx);
  float cold1 = ldf_c(P.c + (size_t)(r0 + 1) * H_ + n0 + tx);

  const float* aBase = P.attp + (size_t)(m0 + arow) * H_ + akq;
  const float* wBase = P.W_ac + (size_t)kk * H4_ + n0 + c8;

  float acc[2][4] = {};

  f4 aN1 = ld_c(aBase);
  f4 aN2 = ld_c(aBase + 32);
  float b0N = wBase[0], b1N = wBase[512], b2N = wBase[1024], b3N = wBase[1536];

  int buf = 0;
  for (int sl = 0; sl < 16; ++sl) {
    f4 aCur = aN1; aN1 = aN2;
    float b0C = b0N, b1C = b1N, b2C = b2N, b3C = b3N;
    if (sl + 2 < 16) aN2 = ld_c(aBase + (size_t)(sl + 2) * 32);
    if (sl + 1 < 16) {
      const float* wp = wBase + (size_t)(sl + 1) * 32 * H4_;
      b0N = wp[0]; b1N = wp[512]; b2N = wp[1024]; b3N = wp[1536];
    }
    #pragma unroll
    for (int i = 0; i < 4; ++i) {
      int gk = sl * 32 + akq + i;
      aCur[i] = aCur[i] * scl[gk] + shf[gk];
    }
    *(f4*)&As[buf][arow][akq] = aCur;
    f4 bv = {b0C, b1C, b2C, b3C};
    *(f4*)&Bs[buf][kk][c8 * 4] = bv;
    __syncthreads();
    #pragma unroll
    for (int k = 0; k < 32; k += 2) {
      f2 a0 = *(const f2*)&As[buf][ty * 2][k];
      f2 a1 = *(const f2*)&As[buf][ty * 2 + 1][k];
      f4 bv0 = *(const f4*)&Bs[buf][k][tx * 4];
      f4 bv1 = *(const f4*)&Bs[buf][k + 1][tx * 4];
      #pragma unroll
      for (int gg = 0; gg < 4; ++gg) {
        acc[0][gg] = fmaf(a0[0], bv0[gg], acc[0][gg]);
        acc[0][gg] = fmaf(a0[1], bv1[gg], acc[0][gg]);
        acc[1][gg] = fmaf(a1[0], bv0[gg], acc[1][gg]);
        acc[1][gg] = fmaf(a1[1], bv1[gg], acc[1][gg]);
      }
    }
    buf ^= 1;
  }

  // ---- fused gates + c/hv + BN-post partials ----
  float s = 0.f, s2 = 0.f;
  #pragma unroll
  for (int i = 0; i < 2; ++i) {
    float vA = acc[i][0] + am[i][0];
    float vF = acc[i][1] + am[i][1];
    float vI = acc[i][2] + am[i][2];
    float vO = acc[i][3] + am[i][3];
    float iv = tanhf(vA);
    float fg = sigf(vF), ig = sigf(vI), og = sigf(vO);
    float cold = i ? cold1 : cold0;
    float cnew = iv * ig + cold * fg;
    const size_t ci = (size_t)(r0 + i) * H_ + n0 + tx;
    stf_c(P.c + ci, cnew);
    float hv = og * eluf(cnew);
    stf_c(P.hv + ci, hv);
    s += hv; s2 += hv * hv;
  }
  float* Af = (float*)As;
  float* Bf = (float*)Bs;
  __syncthreads();
  Af[ty * 16 + tx] = s;
  Bf[ty * 16 + tx] = s2;
  __syncthreads();
  #pragma unroll
  for (int off = 16; off >= 1; off >>= 1) {
    if (ty < off) {
      Af[ty * 16 + tx] += Af[(ty + off) * 16 + tx];
      Bf[ty * 16 + tx] += Bf[(ty + off) * 16 + tx];
    }
    __syncthreads();
  }
  if (tid < 16) {
    const int tm = m0 >> 6;
    stf_c(P.stP + tm * 1024 + n0 + tid, Af[tid]);
    stf_c(P.stP + tm * 1024 + 512 + n0 + tid, Bf[tid]);
  }
}

__global__ __launch_bounds__(NTHR, 4) void larnn(Params P) {
  __shared__ float As[2][64][36];
  __shared__ float Bs[2][32][68];
  __shared__ float scl[H_], shf[H_];
  __shared__ float Qs[H_];
  __shared__ float sc_[8][16], aw_[8][16];

  const int bid = blockIdx.x, tid = threadIdx.x;
  unsigned g = 0;

  for (int t = 0; t < T_; ++t) {
    const float* xt = P.x + (size_t)t * B_ * F_;
    const int slot = (t - 1) & 15;

    // ===== P1: q[0,64) | K[64,128) | V[128,192) | preHF[192,448) | copy[448,480) =====
    if (bid < 64) {
      if (t > 0) { prep4(P.stP, P.g_post, P.be_post, scl, shf, tid); __syncthreads(); }
      GJ J = {}; J.A1 = xt; J.lda1 = F_; J.K1 = F_;
      if (t > 0) { J.A2 = P.hv; J.lda2 = H_; J.K2 = H_; J.nrm2 = 1; J.cg2 = 1; }
      J.W1 = P.Wq_in; J.W2 = P.Wq_in + (size_t)F_ * H_;
      J.b1 = P.bq_in; J.out = P.q; J.N = H_;
      J.m0 = (bid >> 4) * 64; J.n0 = (bid & 15) * 32; J.doElu = 1;
      gemm_tile(J, tid, As, Bs, scl, shf);
    } else if (bid < 128) {
      int l = bid - 64;
      GJ J = {}; J.A1 = P.c; J.lda1 = H_; J.K1 = H_; J.cg1 = 1;
      J.W1 = P.Wk; J.b1 = P.bk; J.out = P.Kbuf + (size_t)slot * BH_; J.N = H_;
      J.m0 = (l >> 4) * 64; J.n0 = (l & 15) * 32; J.doElu = 1;
      gemm_tile(J, tid, As, Bs, scl, shf);
    } else if (bid < 192) {
      int l = bid - 128;
      GJ J = {}; J.A1 = P.c; J.lda1 = H_; J.K1 = H_; J.cg1 = 1;
      J.W1 = P.Wv; J.b1 = P.bv; J.out = P.Vbuf + (size_t)slot * BH_; J.N = H_;
      J.m0 = (l >> 4) * 64; J.n0 = (l & 15) * 32; J.doElu = 1;
      gemm_tile(J, tid, As, Bs, scl, shf);
    } else if (bid < 448) {
      if (t > 0) { prep4(P.stP, P.g_post, P.be_post, scl, shf, tid); __syncthreads(); }
      const int ix = bid - 192;
      GJ J = {}; J.A1 = xt; J.lda1 = F_; J.K1 = F_;
      if (t > 0) { J.A2 = P.hv; J.lda2 = H_; J.K2 = H_; J.nrm2 = 1; J.cg2 = 1; }
      J.W1 = P.W_ih; J.W2 = P.W_hh;
      J.b1 = P.b_ih; J.b2 = P.b_ac; J.out = P.pre; J.N = H4_;
      J.m0 = (ix >> 6) * 64; J.n0 = (ix & 63) * 32;
      gemm_tile(J, tid, As, Bs, scl, shf);
    } else if (bid < 480 && t > 0) {
      prep4(P.stP, P.g_post, P.be_post, scl, shf, tid);
      __syncthreads();
      const int rb0 = (bid - 448) * 8;
      for (int idx = tid; idx < 1024; idx += NTHR) {
        int r = rb0 + (idx >> 7), cc = (idx & 127) * 4;
        f4 hvv = ld_c(P.hv + (size_t)r * H_ + cc);
        f4 v;
        #pragma unroll
        for (int i = 0; i < 4; ++i) v[i] = hvv[i] * scl[cc + i] + shf[cc + i];
        *(f4*)(P.out + (size_t)(t - 1) * BH_ + (size_t)r * H_ + cc) = v;
      }
    }
    gbar(P.arr, P.gen, ++g);

    // =========== P2: Qh = q@Wq + bq (64 blocks) ===========
    if (bid < 64) {
      GJ J = {}; J.A1 = P.q; J.lda1 = H_; J.K1 = H_; J.cg1 = 1;
      J.W1 = P.Wq; J.b1 = P.bq; J.out = P.Qh; J.N = H_;
      J.m0 = (bid >> 4) * 64; J.n0 = (bid & 15) * 32;
      gemm_tile(J, tid, As, Bs, scl, shf);
    }
    gbar(P.arr, P.gen, ++g);

    // =========== P3: attention (1 batch row / block, bid < 256) ===========
    if (bid < B_) {
      const int b = bid;
      const int nv = (t + 1 < W_) ? t + 1 : W_;
      if (tid < 128) *(f4*)&Qs[tid * 4] = ld_c(P.Qh + (size_t)b * H_ + tid * 4);
      __syncthreads();
      {
        const int p = tid >> 2, l4 = tid & 3;
        const int hh = p >> 4, w = p & 15;
        if (w < nv) {
          const int sl = (t - 1 - w) & 15;
          const float* kp = P.Kbuf + ((size_t)sl * B_ + b) * H_ + hh * 64 + l4 * 16;
          const float* qp = Qs + hh * 64 + l4 * 16;
          float s = 0.f;
          #pragma unroll
          for (int d = 0; d < 16; d += 4) {
            f4 kv = ld_c(kp + d);
            f4 qv = *(const f4*)(qp + d);
            s = fmaf(kv[0], qv[0], fmaf(kv[1], qv[1], fmaf(kv[2], qv[2], fmaf(kv[3], qv[3], s))));
          }
          s += __shfl_xor(s, 1); s += __shfl_xor(s, 2);
          if (l4 == 0) sc_[hh][w] = s * 0.125f;
        }
      }
      __syncthreads();
      if (tid < 8) {
        float mx = -1e30f;
        for (int w = 0; w < nv; ++w) mx = fmaxf(mx, sc_[tid][w]);
        float ss = 0.f;
        for (int w = 0; w < nv; ++w) { float e = expf(sc_[tid][w] - mx); aw_[tid][w] = e; ss += e; }
        float inv = 1.f / ss;
        for (int w = 0; w < nv; ++w) aw_[tid][w] *= inv;
      }
      __syncthreads();
      {
        const int j = tid, hh = j >> 6;
        float o = 0.f;
        for (int w = 0; w < nv; ++w) {
          const int sl = (t - 1 - w) & 15;
          o = fmaf(aw_[hh][w], ldf_c(P.Vbuf + ((size_t)sl * B_ + b) * H_ + j), o);
        }
        stf_c(P.ctx + (size_t)b * H_ + j, o);
      }
    }
    gbar(P.arr, P.gen, ++g);

    // =========== P4: attp = elu(ctx@Wo + bo) + BN partials (64 blocks) ===========
    if (bid < 64) {
      GJ J = {}; J.A1 = P.ctx; J.lda1 = H_; J.K1 = H_; J.cg1 = 1;
      J.W1 = P.Wo; J.b1 = P.bo; J.doElu = 1;
      J.out = P.attp; J.stats = P.stA; J.N = H_;
      J.m0 = (bid >> 4) * 64; J.n0 = (bid & 15) * 32;
      gemm_tile(J, tid, As, Bs, scl, shf);
    }
    gbar(P.arr, P.gen, ++g);

    // =========== P5: pre-gates GEMM + fused gates (128 blocks) ===========
    if (bid < 128) {
      prep4(P.stA, P.g_att, P.be_att, scl, shf, tid);
      __syncthreads();
      gemm_gates(P, tid, bid, As, Bs, scl, shf);
    }
    gbar(P.arr, P.gen, ++g);
  }

  // =========== final out-copy for t = 127 ===========
  if (bid >= 448 && bid < 480) {
    prep4(P.stP, P.g_post, P.be_post, scl, shf, tid);
    __syncthreads();
    const int rb0 = (bid - 448) * 8;
    for (int idx = tid; idx < 1024; idx += NTHR) {
      int r = rb0 + (idx >> 7), cc = (idx & 127) * 4;
      f4 hvv = ld_c(P.hv + (size_t)r * H_ + cc);
      f4 v;
      #pragma unroll
      for (int i = 0; i < 4; ++i) v[i] = hvv[i] * scl[cc + i] + shf[cc + i];
      *(f4*)(P.out + (size_t)127 * BH_ + (size_t)r * H_ + cc) = v;
    }
  }
}

#define SYNC_UINTS (32 + NBLK * FSTRIDE)   // gen line + 512 padded flags

__global__ __launch_bounds__(256) void pinit(float* c, unsigned* sync) {
  const int i = blockIdx.x * 256 + threadIdx.x;
  if (i < BH_) c[i] = 0.f;
  if (i < SYNC_UINTS) sync[i] = 0u;
}

extern "C" void kernel_launch(void* const* d_in, const int* in_sizes, int n_in,
                              void* d_out, int out_size, void* d_ws, size_t ws_size,
                              hipStream_t stream) {
  Params P;
  P.x      = (const float*)d_in[0];
  P.W_ih   = (const float*)d_in[1];
  P.b_ih   = (const float*)d_in[2];
  P.W_hh   = (const float*)d_in[3];
  P.Wq_in  = (const float*)d_in[4];
  P.bq_in  = (const float*)d_in[5];
  P.Wq     = (const float*)d_in[6];
  P.bq     = (const float*)d_in[7];
  P.Wk     = (const float*)d_in[8];
  P.bk     = (const float*)d_in[9];
  P.Wv     = (const float*)d_in[10];
  P.bv     = (const float*)d_in[11];
  P.Wo     = (const float*)d_in[12];
  P.bo     = (const float*)d_in[13];
  P.W_ac   = (const float*)d_in[14];
  P.b_ac   = (const float*)d_in[15];
  P.g_att  = (const float*)d_in[16];
  P.be_att = (const float*)d_in[17];
  P.g_post = (const float*)d_in[18];
  P.be_post= (const float*)d_in[19];
  P.out    = (float*)d_out;

  unsigned* sync = (unsigned*)d_ws;
  P.gen = sync;                    // own 128B line
  P.arr = sync + 32;               // 512 flags, 128B stride
  float* fb = (float*)d_ws + SYNC_UINTS;
  P.c    = fb;                 fb += BH_;
  P.q    = fb;                 fb += BH_;
  P.Qh   = fb;                 fb += BH_;
  P.ctx  = fb;                 fb += BH_;
  P.attp = fb;                 fb += BH_;
  P.hv   = fb;                 fb += BH_;
  P.pre  = fb;                 fb += (size_t)B_ * H4_;
  P.Kbuf = fb;                 fb += (size_t)W_ * BH_;
  P.Vbuf = fb;                 fb += (size_t)W_ * BH_;
  P.stA  = fb;                 fb += 4096;
  P.stP  = fb;                 fb += 4096;

  pinit<<<(BH_ + 255) / 256, 256, 0, stream>>>(P.c, sync);
  larnn<<<NBLK, NTHR, 0, stream>>>(P);
}

// Round 18
// 15832.991 us; speedup vs baseline: 1.7821x; 1.7821x over previous
//
#include <hip/hip_runtime.h>
#include <math.h>

// ============================================================================
// LARNN forward, MI355X — persistent kernel, fence-free sc1.
// ALL-F32 (bf16 diverges — chaotic recurrence). Deterministic BN stats.
// Round 18 = round-16 base (15.82 ms verified) with P2/P3/P4 merged into ONE
// phase via fine-grained flags on DISJOINT block sets:
//   Qh: blocks 256-319 (were idle) -> per-tile flags qfl[64]
//   attention: blocks 0-255, polls its m-tile's 16 qfl, sets cfl[b]
//   Wo: blocks 320-383, polls its 64 ctx-row cfl
// 4 barriers/step (was 6); pipeline overlap of the 3 latency chains.
// All GEMM/attention code byte-identical to r16 (r17's fused-gates access
// pattern regressed 2x from uncoalesced weight reads — reverted).
// ============================================================================

#define T_  128
#define B_  256
#define F_  128
#define H_  512
#define W_  16
#define H4_ 2048
#define EPS_ 1e-5f
#define BH_ (B_*H_)
#define NBLK 512
#define NTHR 512
#define FSTRIDE 32   // uints per flag (128B line)

typedef __attribute__((ext_vector_type(4))) float f4;
typedef __attribute__((ext_vector_type(2))) float f2;
typedef unsigned long long u64;

__device__ __forceinline__ float eluf(float x){ return x > 0.f ? x : expf(x) - 1.f; }
__device__ __forceinline__ float sigf(float x){ return 1.f / (1.f + expf(-x)); }

// ---- LLC-coherent (sc1) relaxed accessors: no cache maintenance emitted ----
__device__ __forceinline__ f4 ld_c(const float* p) {
  union { f4 v; u64 q[2]; } u;
  u.q[0] = __hip_atomic_load((const u64*)p,     __ATOMIC_RELAXED, __HIP_MEMORY_SCOPE_AGENT);
  u.q[1] = __hip_atomic_load((const u64*)p + 1, __ATOMIC_RELAXED, __HIP_MEMORY_SCOPE_AGENT);
  return u.v;
}
__device__ __forceinline__ void st_c(float* p, f4 v) {
  union { f4 v; u64 q[2]; } u; u.v = v;
  __hip_atomic_store((u64*)p,     u.q[0], __ATOMIC_RELAXED, __HIP_MEMORY_SCOPE_AGENT);
  __hip_atomic_store((u64*)p + 1, u.q[1], __ATOMIC_RELAXED, __HIP_MEMORY_SCOPE_AGENT);
}
__device__ __forceinline__ f2 ld2_c(const float* p) {
  union { u64 q; f2 v; } u;
  u.q = __hip_atomic_load((const u64*)p, __ATOMIC_RELAXED, __HIP_MEMORY_SCOPE_AGENT);
  return u.v;
}
__device__ __forceinline__ void st2_c(float* p, f2 v) {
  union { f2 v; u64 q; } u; u.v = v;
  __hip_atomic_store((u64*)p, u.q, __ATOMIC_RELAXED, __HIP_MEMORY_SCOPE_AGENT);
}
__device__ __forceinline__ float ldf_c(const float* p) {
  unsigned u = __hip_atomic_load((const unsigned*)p, __ATOMIC_RELAXED, __HIP_MEMORY_SCOPE_AGENT);
  return __uint_as_float(u);
}
__device__ __forceinline__ void stf_c(float* p, float v) {
  __hip_atomic_store((unsigned*)p, __float_as_uint(v), __ATOMIC_RELAXED, __HIP_MEMORY_SCOPE_AGENT);
}
__device__ __forceinline__ unsigned ldu_c(const unsigned* p) {
  return __hip_atomic_load(p, __ATOMIC_RELAXED, __HIP_MEMORY_SCOPE_AGENT);
}
__device__ __forceinline__ void stu_c(unsigned* p, unsigned v) {
  __hip_atomic_store(p, v, __ATOMIC_RELAXED, __HIP_MEMORY_SCOPE_AGENT);
}

struct Params {
  const float *x, *W_ih, *b_ih, *W_hh, *Wq_in, *bq_in, *Wq, *bq, *Wk, *bk,
              *Wv, *bv, *Wo, *bo, *W_ac, *b_ac, *g_att, *be_att, *g_post, *be_post;
  float *out, *c, *q, *Qh, *ctx, *attp, *hv, *pre, *Kbuf, *Vbuf, *stA, *stP;
  unsigned *gen, *arr, *qfl, *cfl;
};

// Barrier: flag store + block-0 parallel aggregation + gen release.
__device__ __forceinline__ void gbar(unsigned* arr, unsigned* gen, unsigned g) {
  asm volatile("s_waitcnt vmcnt(0) lgkmcnt(0)" ::: "memory");
  __syncthreads();
  const int tid = threadIdx.x;
  if (tid == 0)
    __hip_atomic_store(&arr[blockIdx.x * FSTRIDE], g, __ATOMIC_RELAXED, __HIP_MEMORY_SCOPE_AGENT);
  if (blockIdx.x == 0) {
    if (tid < NBLK) {
      while (__hip_atomic_load(&arr[tid * FSTRIDE], __ATOMIC_RELAXED, __HIP_MEMORY_SCOPE_AGENT) < g)
        __builtin_amdgcn_s_sleep(1);
    }
    __syncthreads();
    if (tid == 0)
      __hip_atomic_store(gen, g, __ATOMIC_RELAXED, __HIP_MEMORY_SCOPE_AGENT);
  } else {
    if (tid == 0) {
      while (__hip_atomic_load(gen, __ATOMIC_RELAXED, __HIP_MEMORY_SCOPE_AGENT) < g)
        __builtin_amdgcn_s_sleep(1);
    }
  }
  __syncthreads();
}

// Producer: drain stores, then set flag (tid 0).
__device__ __forceinline__ void set_flag(unsigned* fl, unsigned v, int tid) {
  asm volatile("s_waitcnt vmcnt(0) lgkmcnt(0)" ::: "memory");
  __syncthreads();
  if (tid == 0) stu_c(fl, v);
}

// BN scale/shift from single-partial stats stP[2][512] (gates output).
__device__ __forceinline__ void prepP(const float* stP, const float* gn, const float* be,
                                      float* scl, float* shf, int tid) {
  if (tid < H_) {
    float S  = ldf_c(stP + tid);
    float S2 = ldf_c(stP + H_ + tid);
    float mu  = S * (1.f / B_);
    float var = S2 * (1.f / B_) - mu * mu;
    float sc  = rsqrtf(var + EPS_) * gn[tid];
    scl[tid] = sc; shf[tid] = be[tid] - mu * sc;
  }
}

// BN scale/shift from 4-way partial stats stA[4][2][512] (Wo GEMM output).
__device__ __forceinline__ void prepA(const float* stA, const float* gn, const float* be,
                                      float* scl, float* shf, int tid) {
  if (tid < H_) {
    float S  = ldf_c(stA + tid) + ldf_c(stA + 1024 + tid) + ldf_c(stA + 2048 + tid) + ldf_c(stA + 3072 + tid);
    float S2 = ldf_c(stA + 512 + tid) + ldf_c(stA + 1536 + tid) + ldf_c(stA + 2560 + tid) + ldf_c(stA + 3584 + tid);
    float mu  = S * (1.f / B_);
    float var = S2 * (1.f / B_) - mu * mu;
    float sc  = rsqrtf(var + EPS_) * gn[tid];
    scl[tid] = sc; shf[tid] = be[tid] - mu * sc;
  }
}

// ---------------------------------------------------------------------------
// 64x32 output tile, K-concat of up to 2 segments, 512 threads, 2x2 microtile.
// (Byte-identical to r16.)
// ---------------------------------------------------------------------------
struct GJ {
  const float* A1; int lda1; int K1; int nrm1; int cg1;
  const float* A2; int lda2; int K2; int nrm2; int cg2;
  const float* W1; const float* W2;    // [K][N] row-major, stride N (plain)
  const float* b1; const float* b2; const float* addm;
  float* out; float* stats;
  int N; int m0; int n0; int doElu;
};

__device__ void gemm_tile(const GJ& J, int tid,
                          float (*As)[64][36], float (*Bs)[32][36],
                          const float* scl, const float* shf) {
  const int arow = tid >> 3, akq = (tid & 7) * 4;
  const int bkk = tid >> 4, bnn = (tid & 15) * 2;
  const int ty = tid >> 4, tx = tid & 15;

  float acc[2][2] = {{0.f,0.f},{0.f,0.f}};

  f2 am0 = {0.f,0.f}, am1 = {0.f,0.f};
  if (J.addm) {
    am0 = ld2_c(J.addm + (size_t)(J.m0 + ty * 2)     * J.N + J.n0 + tx * 2);
    am1 = ld2_c(J.addm + (size_t)(J.m0 + ty * 2 + 1) * J.N + J.n0 + tx * 2);
  }

  int buf = 0;
  for (int s = 0; s < 2; ++s) {
    const float* A = s ? J.A2 : J.A1;
    if (!A) break;
    const float* Wp  = s ? J.W2 : J.W1;
    const int K      = s ? J.K2 : J.K1;
    const int lda    = s ? J.lda2 : J.lda1;
    const int nrm    = s ? J.nrm2 : J.nrm1;
    const int cg     = s ? J.cg2 : J.cg1;
    const int nsl    = K >> 5;

    const float* aBase = A + (size_t)(J.m0 + arow) * lda + akq;
    const float* wBase = Wp + (size_t)bkk * J.N + J.n0 + bnn;
    const size_t wSlab = (size_t)32 * J.N;

    f4 aN1 = cg ? ld_c(aBase) : *(const f4*)aBase;
    f4 aN2 = (nsl > 1) ? (cg ? ld_c(aBase + 32) : *(const f4*)(aBase + 32)) : aN1;
    f2 bN1 = *(const f2*)wBase;

    for (int sl = 0; sl < nsl; ++sl) {
      f4 aCur = aN1; aN1 = aN2;
      f2 bCur = bN1;
      if (sl + 2 < nsl) {
        const float* ap = aBase + (size_t)(sl + 2) * 32;
        aN2 = cg ? ld_c(ap) : *(const f4*)ap;
      }
      if (sl + 1 < nsl) bN1 = *(const f2*)(wBase + (size_t)(sl + 1) * wSlab);
      if (nrm) {
        #pragma unroll
        for (int i = 0; i < 4; ++i) {
          int gk = sl * 32 + akq + i;
          aCur[i] = aCur[i] * scl[gk] + shf[gk];
        }
      }
      *(f4*)&As[buf][arow][akq] = aCur;
      *(f2*)&Bs[buf][bkk][bnn] = bCur;
      __syncthreads();
      #pragma unroll
      for (int k = 0; k < 32; k += 2) {
        f2 a0 = *(const f2*)&As[buf][ty * 2][k];
        f2 a1 = *(const f2*)&As[buf][ty * 2 + 1][k];
        f2 b0 = *(const f2*)&Bs[buf][k][tx * 2];
        f2 b1 = *(const f2*)&Bs[buf][k + 1][tx * 2];
        acc[0][0] = fmaf(a0[0], b0[0], acc[0][0]);
        acc[0][1] = fmaf(a0[0], b0[1], acc[0][1]);
        acc[0][0] = fmaf(a0[1], b1[0], acc[0][0]);
        acc[0][1] = fmaf(a0[1], b1[1], acc[0][1]);
        acc[1][0] = fmaf(a1[0], b0[0], acc[1][0]);
        acc[1][1] = fmaf(a1[0], b0[1], acc[1][1]);
        acc[1][0] = fmaf(a1[1], b1[0], acc[1][0]);
        acc[1][1] = fmaf(a1[1], b1[1], acc[1][1]);
      }
      buf ^= 1;
    }
  }

  const int r0 = J.m0 + ty * 2, c0 = J.n0 + tx * 2;
  f2 bias = {0.f, 0.f};
  if (J.b1) bias += *(const f2*)(J.b1 + c0);
  if (J.b2) bias += *(const f2*)(J.b2 + c0);
  f2 v0, v1;
  v0[0] = acc[0][0] + bias[0]; v0[1] = acc[0][1] + bias[1];
  v1[0] = acc[1][0] + bias[0]; v1[1] = acc[1][1] + bias[1];
  if (J.addm) { v0 += am0; v1 += am1; }
  if (J.doElu) {
    v0[0] = eluf(v0[0]); v0[1] = eluf(v0[1]);
    v1[0] = eluf(v1[0]); v1[1] = eluf(v1[1]);
  }
  st2_c(J.out + (size_t)r0 * J.N + c0, v0);
  st2_c(J.out + (size_t)(r0 + 1) * J.N + c0, v1);

  if (J.stats) {   // deterministic per-64-row-tile column partials (32 cols)
    float* Af = (float*)As;
    float* Bf = (float*)Bs;
    __syncthreads();
    Af[ty * 32 + tx * 2]     = v0[0] + v1[0];
    Af[ty * 32 + tx * 2 + 1] = v0[1] + v1[1];
    Bf[ty * 32 + tx * 2]     = v0[0] * v0[0] + v1[0] * v1[0];
    Bf[ty * 32 + tx * 2 + 1] = v0[1] * v0[1] + v1[1] * v1[1];
    __syncthreads();
    if (tid < 32) {
      float S = 0.f, S2 = 0.f;
      #pragma unroll
      for (int y = 0; y < 32; ++y) { S += Af[y * 32 + tid]; S2 += Bf[y * 32 + tid]; }
      const int tm = J.m0 >> 6;
      stf_c(J.stats + tm * 1024 + J.n0 + tid, S);
      stf_c(J.stats + tm * 1024 + 512 + J.n0 + tid, S2);
    }
  }
}

__global__ __launch_bounds__(NTHR, 4) void larnn(Params P) {
  __shared__ float As[2][64][36];
  __shared__ float Bs[2][32][36];
  __shared__ float scl[H_], shf[H_];
  __shared__ float Qs[H_];
  __shared__ float sc_[8][16], aw_[8][16];

  const int bid = blockIdx.x, tid = threadIdx.x;
  unsigned g = 0;

  for (int t = 0; t < T_; ++t) {
    const float* xt = P.x + (size_t)t * B_ * F_;
    const int slot = (t - 1) & 15;
    const unsigned fv = (unsigned)(t + 1);

    // ===== P1: q[0,64) | K[64,128) | V[128,192) | preHF[192,448) | copy[448,480) =====
    if (bid < 64) {
      if (t > 0) { prepP(P.stP, P.g_post, P.be_post, scl, shf, tid); __syncthreads(); }
      GJ J = {}; J.A1 = xt; J.lda1 = F_; J.K1 = F_;
      if (t > 0) { J.A2 = P.hv; J.lda2 = H_; J.K2 = H_; J.nrm2 = 1; J.cg2 = 1; }
      J.W1 = P.Wq_in; J.W2 = P.Wq_in + (size_t)F_ * H_;
      J.b1 = P.bq_in; J.out = P.q; J.N = H_;
      J.m0 = (bid >> 4) * 64; J.n0 = (bid & 15) * 32; J.doElu = 1;
      gemm_tile(J, tid, As, Bs, scl, shf);
    } else if (bid < 128) {
      int l = bid - 64;
      GJ J = {}; J.A1 = P.c; J.lda1 = H_; J.K1 = H_; J.cg1 = 1;
      J.W1 = P.Wk; J.b1 = P.bk; J.out = P.Kbuf + (size_t)slot * BH_; J.N = H_;
      J.m0 = (l >> 4) * 64; J.n0 = (l & 15) * 32; J.doElu = 1;
      gemm_tile(J, tid, As, Bs, scl, shf);
    } else if (bid < 192) {
      int l = bid - 128;
      GJ J = {}; J.A1 = P.c; J.lda1 = H_; J.K1 = H_; J.cg1 = 1;
      J.W1 = P.Wv; J.b1 = P.bv; J.out = P.Vbuf + (size_t)slot * BH_; J.N = H_;
      J.m0 = (l >> 4) * 64; J.n0 = (l & 15) * 32; J.doElu = 1;
      gemm_tile(J, tid, As, Bs, scl, shf);
    } else if (bid < 448) {
      if (t > 0) { prepP(P.stP, P.g_post, P.be_post, scl, shf, tid); __syncthreads(); }
      const int ix = bid - 192;
      GJ J = {}; J.A1 = xt; J.lda1 = F_; J.K1 = F_;
      if (t > 0) { J.A2 = P.hv; J.lda2 = H_; J.K2 = H_; J.nrm2 = 1; J.cg2 = 1; }
      J.W1 = P.W_ih; J.W2 = P.W_hh;
      J.b1 = P.b_ih; J.b2 = P.b_ac; J.out = P.pre; J.N = H4_;
      J.m0 = (ix >> 6) * 64; J.n0 = (ix & 63) * 32;
      gemm_tile(J, tid, As, Bs, scl, shf);
    } else if (bid < 480 && t > 0) {
      prepP(P.stP, P.g_post, P.be_post, scl, shf, tid);
      __syncthreads();
      const int rb0 = (bid - 448) * 8;
      for (int idx = tid; idx < 1024; idx += NTHR) {
        int r = rb0 + (idx >> 7), cc = (idx & 127) * 4;
        f4 hvv = ld_c(P.hv + (size_t)r * H_ + cc);
        f4 v;
        #pragma unroll
        for (int i = 0; i < 4; ++i) v[i] = hvv[i] * scl[cc + i] + shf[cc + i];
        *(f4*)(P.out + (size_t)(t - 1) * BH_ + (size_t)r * H_ + cc) = v;
      }
    }
    gbar(P.arr, P.gen, ++g);

    // ===== P2': Qh[256,320) -> qfl | attn[0,256) qfl->cfl | Wo[320,384) cfl =====
    if (bid >= 256 && bid < 320) {
      const int l = bid - 256;
      GJ J = {}; J.A1 = P.q; J.lda1 = H_; J.K1 = H_; J.cg1 = 1;
      J.W1 = P.Wq; J.b1 = P.bq; J.out = P.Qh; J.N = H_;
      J.m0 = (l >> 4) * 64; J.n0 = (l & 15) * 32;
      gemm_tile(J, tid, As, Bs, scl, shf);
      set_flag(P.qfl + l * FSTRIDE, fv, tid);
    } else if (bid < 256) {
      const int b = bid;
      const int nv = (t + 1 < W_) ? t + 1 : W_;
      if (tid < 16) {
        const unsigned* fp = P.qfl + ((b >> 6) * 16 + tid) * FSTRIDE;
        while (ldu_c(fp) < fv) __builtin_amdgcn_s_sleep(1);
      }
      __syncthreads();
      if (tid < 128) *(f4*)&Qs[tid * 4] = ld_c(P.Qh + (size_t)b * H_ + tid * 4);
      __syncthreads();
      {
        const int p = tid >> 2, l4 = tid & 3;
        const int hh = p >> 4, w = p & 15;
        if (w < nv) {
          const int sl = (t - 1 - w) & 15;
          const float* kp = P.Kbuf + ((size_t)sl * B_ + b) * H_ + hh * 64 + l4 * 16;
          const float* qp = Qs + hh * 64 + l4 * 16;
          float s = 0.f;
          #pragma unroll
          for (int d = 0; d < 16; d += 4) {
            f4 kv = ld_c(kp + d);
            f4 qv = *(const f4*)(qp + d);
            s = fmaf(kv[0], qv[0], fmaf(kv[1], qv[1], fmaf(kv[2], qv[2], fmaf(kv[3], qv[3], s))));
          }
          s += __shfl_xor(s, 1); s += __shfl_xor(s, 2);
          if (l4 == 0) sc_[hh][w] = s * 0.125f;
        }
      }
      __syncthreads();
      if (tid < 8) {
        float mx = -1e30f;
        for (int w = 0; w < nv; ++w) mx = fmaxf(mx, sc_[tid][w]);
        float ss = 0.f;
        for (int w = 0; w < nv; ++w) { float e = expf(sc_[tid][w] - mx); aw_[tid][w] = e; ss += e; }
        float inv = 1.f / ss;
        for (int w = 0; w < nv; ++w) aw_[tid][w] *= inv;
      }
      __syncthreads();
      {
        const int j = tid, hh = j >> 6;
        float o = 0.f;
        for (int w = 0; w < nv; ++w) {
          const int sl = (t - 1 - w) & 15;
          o = fmaf(aw_[hh][w], ldf_c(P.Vbuf + ((size_t)sl * B_ + b) * H_ + j), o);
        }
        stf_c(P.ctx + (size_t)b * H_ + j, o);
      }
      set_flag(P.cfl + b * FSTRIDE, fv, tid);
    } else if (bid >= 320 && bid < 384) {
      const int l = bid - 320;
      if (tid < 64) {
        const unsigned* fp = P.cfl + ((l >> 4) * 64 + tid) * FSTRIDE;
        while (ldu_c(fp) < fv) __builtin_amdgcn_s_sleep(1);
      }
      __syncthreads();
      GJ J = {}; J.A1 = P.ctx; J.lda1 = H_; J.K1 = H_; J.cg1 = 1;
      J.W1 = P.Wo; J.b1 = P.bo; J.doElu = 1;
      J.out = P.attp; J.stats = P.stA; J.N = H_;
      J.m0 = (l >> 4) * 64; J.n0 = (l & 15) * 32;
      gemm_tile(J, tid, As, Bs, scl, shf);
    }
    gbar(P.arr, P.gen, ++g);

    // =========== P5: pre += BN(attp)@W_ac (256 blocks) ===========
    if (bid < 256) {
      prepA(P.stA, P.g_att, P.be_att, scl, shf, tid);
      __syncthreads();
      GJ J = {}; J.A1 = P.attp; J.lda1 = H_; J.K1 = H_; J.cg1 = 1; J.nrm1 = 1;
      J.W1 = P.W_ac; J.addm = P.pre; J.out = P.pre; J.N = H4_;
      J.m0 = (bid >> 6) * 64; J.n0 = (bid & 63) * 32;
      gemm_tile(J, tid, As, Bs, scl, shf);
    }
    gbar(P.arr, P.gen, ++g);

    // =========== P6: gates + c/hv + BN-post stats (64 blocks) ===========
    if (bid < 64) {
      f4* rS = (f4*)As;
      f4* rQ = (f4*)Bs;
      const int sub = tid & 1, r = tid >> 1;
      const int c4 = bid * 8 + sub * 4;
      const size_t rb = (size_t)r * H4_;
      f4 p0 = ld_c(P.pre + rb + c4);
      f4 pf = ld_c(P.pre + rb + c4 + 512);
      f4 pi = ld_c(P.pre + rb + c4 + 1024);
      f4 po = ld_c(P.pre + rb + c4 + 1536);
      const size_t ci = (size_t)r * H_ + c4;
      f4 cold = ld_c(P.c + ci);
      f4 cn, hvv;
      #pragma unroll
      for (int i = 0; i < 4; ++i) {
        float iv = tanhf(p0[i]);
        float fg = sigf(pf[i]), ig = sigf(pi[i]), og = sigf(po[i]);
        cn[i] = iv * ig + cold[i] * fg;
        hvv[i] = og * eluf(cn[i]);
      }
      st_c(P.c + ci, cn);
      st_c(P.hv + ci, hvv);
      rS[sub * 256 + r] = hvv;
      rQ[sub * 256 + r] = hvv * hvv;
      __syncthreads();
      for (int s2 = 128; s2 > 0; s2 >>= 1) {
        if (r < s2) {
          rS[sub * 256 + r] += rS[sub * 256 + r + s2];
          rQ[sub * 256 + r] += rQ[sub * 256 + r + s2];
        }
        __syncthreads();
      }
      if (r == 0) {
        f4 S = rS[sub * 256], Q2 = rQ[sub * 256];
        #pragma unroll
        for (int i = 0; i < 4; ++i) { stf_c(P.stP + c4 + i, S[i]); stf_c(P.stP + 512 + c4 + i, Q2[i]); }
      }
    }
    gbar(P.arr, P.gen, ++g);
  }

  // =========== final out-copy for t = 127 ===========
  if (bid >= 448 && bid < 480) {
    prepP(P.stP, P.g_post, P.be_post, scl, shf, tid);
    __syncthreads();
    const int rb0 = (bid - 448) * 8;
    for (int idx = tid; idx < 1024; idx += NTHR) {
      int r = rb0 + (idx >> 7), cc = (idx & 127) * 4;
      f4 hvv = ld_c(P.hv + (size_t)r * H_ + cc);
      f4 v;
      #pragma unroll
      for (int i = 0; i < 4; ++i) v[i] = hvv[i] * scl[cc + i] + shf[cc + i];
      *(f4*)(P.out + (size_t)127 * BH_ + (size_t)r * H_ + cc) = v;
    }
  }
}

// sync area: gen(32) + arr(512*32) + qfl(64*32) + cfl(256*32)
#define SYNC_UINTS (32 + NBLK * FSTRIDE + 64 * FSTRIDE + 256 * FSTRIDE)

__global__ __launch_bounds__(256) void pinit(float* c, unsigned* sync) {
  const int i = blockIdx.x * 256 + threadIdx.x;
  if (i < BH_) c[i] = 0.f;
  if (i < SYNC_UINTS) sync[i] = 0u;
}

extern "C" void kernel_launch(void* const* d_in, const int* in_sizes, int n_in,
                              void* d_out, int out_size, void* d_ws, size_t ws_size,
                              hipStream_t stream) {
  Params P;
  P.x      = (const float*)d_in[0];
  P.W_ih   = (const float*)d_in[1];
  P.b_ih   = (const float*)d_in[2];
  P.W_hh   = (const float*)d_in[3];
  P.Wq_in  = (const float*)d_in[4];
  P.bq_in  = (const float*)d_in[5];
  P.Wq     = (const float*)d_in[6];
  P.bq     = (const float*)d_in[7];
  P.Wk     = (const float*)d_in[8];
  P.bk     = (const float*)d_in[9];
  P.Wv     = (const float*)d_in[10];
  P.bv     = (const float*)d_in[11];
  P.Wo     = (const float*)d_in[12];
  P.bo     = (const float*)d_in[13];
  P.W_ac   = (const float*)d_in[14];
  P.b_ac   = (const float*)d_in[15];
  P.g_att  = (const float*)d_in[16];
  P.be_att = (const float*)d_in[17];
  P.g_post = (const float*)d_in[18];
  P.be_post= (const float*)d_in[19];
  P.out    = (float*)d_out;

  unsigned* sync = (unsigned*)d_ws;
  P.gen = sync;                             // own 128B line
  P.arr = sync + 32;                        // 512 flags
  P.qfl = sync + 32 + NBLK * FSTRIDE;       // 64 Qh-tile flags
  P.cfl = P.qfl + 64 * FSTRIDE;             // 256 ctx-row flags
  float* fb = (float*)d_ws + SYNC_UINTS;
  P.c    = fb;                 fb += BH_;
  P.q    = fb;                 fb += BH_;
  P.Qh   = fb;                 fb += BH_;
  P.ctx  = fb;                 fb += BH_;
  P.attp = fb;                 fb += BH_;
  P.hv   = fb;                 fb += BH_;
  P.pre  = fb;                 fb += (size_t)B_ * H4_;
  P.Kbuf = fb;                 fb += (size_t)W_ * BH_;
  P.Vbuf = fb;                 fb += (size_t)W_ * BH_;
  P.stA  = fb;                 fb += 4096;
  P.stP  = fb;                 fb += 1024;

  pinit<<<(BH_ + 255) / 256, 256, 0, stream>>>(P.c, sync);
  larnn<<<NBLK, NTHR, 0, stream>>>(P);
}